// Round 1
// 864.080 us; speedup vs baseline: 1.1284x; 1.1284x over previous
//
#include <hip/hip_runtime.h>
#include <stdint.h>

#define Bz   2
#define Ss   2048
#define HID  4096
#define NH   32
#define NKV  8
#define HD   128
#define Mrows (Bz*Ss)   // 4096
#define NQKV 6144       // 4096 Q + 1024 K + 1024 V

typedef __attribute__((ext_vector_type(8))) short b16x8;       // 8 bf16 (4 VGPRs)
typedef __attribute__((ext_vector_type(8))) _Float16 f16x8;    // 8 f16  (4 VGPRs)
typedef __attribute__((ext_vector_type(4))) float f32x4;

__device__ __forceinline__ unsigned short f2bf(float f) {
  union { float f; uint32_t u; } v; v.f = f;
  uint32_t r = v.u + 0x7FFFu + ((v.u >> 16) & 1u);   // RNE
  return (unsigned short)(r >> 16);
}

// async global->LDS, 16B per lane; LDS dest = wave-uniform base + lane*16
__device__ __forceinline__ void cp16(const void* g, void* l) {
  __builtin_amdgcn_global_load_lds(
      (const __attribute__((address_space(1))) void*)g,
      (__attribute__((address_space(3))) void*)l, 16, 0, 0);
}

// ---------------- elementwise cast: fp32 -> bf16 (float4 loads) ----------------
__global__ __launch_bounds__(256) void cast_x(const float* __restrict__ x,
                                              unsigned short* __restrict__ o) {
  int i = blockIdx.x*256 + threadIdx.x;
  float4 v = ((const float4*)x)[i];
  ushort4 r; r.x = f2bf(v.x); r.y = f2bf(v.y); r.z = f2bf(v.z); r.w = f2bf(v.w);
  ((ushort4*)o)[i] = r;
}

// ---------------- W[k][n] fp32 -> Wt[n][k] bf16 (32x32 LDS tile) ----------------
__global__ __launch_bounds__(256) void wtrans(const float* __restrict__ W,
                                              unsigned short* __restrict__ Wt,
                                              int K, int N) {
  __shared__ float t[32][33];
  int n0 = blockIdx.x*32, k0 = blockIdx.y*32;
  int tx = threadIdx.x & 31, ty = threadIdx.x >> 5;
#pragma unroll
  for (int i = 0; i < 4; i++)
    t[ty + i*8][tx] = W[(size_t)(k0 + ty + i*8)*N + n0 + tx];
  __syncthreads();
#pragma unroll
  for (int i = 0; i < 4; i++)
    Wt[(size_t)(n0 + ty + i*8)*K + k0 + tx] = f2bf(t[tx][ty + i*8]);
}

// ---------------- bias concat: [bq | bk | bv] ----------------
__global__ __launch_bounds__(256) void bias_cat(const float* __restrict__ bq,
                                                const float* __restrict__ bk,
                                                const float* __restrict__ bv,
                                                float* __restrict__ o) {
  int i = blockIdx.x*256 + threadIdx.x;
  float v = (i < 4096) ? bq[i] : (i < 5120) ? bk[i-4096] : bv[i-5120];
  o[i] = v;
}

// ---------------- C(MxN,f32) = A(MxK,bf16) @ Bt(NxK,bf16)^T + bias ----------------
// 256x256 tile, BK=64, 8 waves (2M x 4N), 128KB double-buffered LDS.
// Counted-vmcnt pipeline (T3+T4): raw s_barrier (no compiler drain); tile t+2 is
// staged into the buffer freed by tile t's last ds_read; s_waitcnt vmcnt(8) before
// the tail barrier guarantees tile t+1 landed while t+2's 8 loads stay in flight.
// LDS swizzle: 16B chunk c of row r stored at c ^ (r&7) (via pre-swizzled global
// src; involution on read). Requires K >= 128 (NT >= 2); both call sites K=4096.
__global__ __launch_bounds__(512, 2) void gemm_bt(const unsigned short* __restrict__ A,
                                                  const unsigned short* __restrict__ Bt,
                                                  const float* __restrict__ bias,
                                                  float* __restrict__ C,
                                                  int N, int K) {
  __shared__ short Al[2][256*64];   // 64KB
  __shared__ short Bl[2][256*64];   // 64KB
  const int tid = threadIdx.x;
  const int w = tid >> 6, lane = tid & 63;
  const int wm = w >> 2, wn = w & 3;
  const int lrow = lane & 15, quad = lane >> 4;
  const int swz = lrow & 7;
  // T1: bijective XCD swizzle (both launches have nwg % 8 == 0)
  int bid = blockIdx.y * gridDim.x + blockIdx.x;
  const int nwg = gridDim.x * gridDim.y;
  bid = (bid & 7) * (nwg >> 3) + (bid >> 3);
  const int m0 = (bid / gridDim.x) * 256;
  const int n0 = (bid % gridDim.x) * 256;
  // staging geometry: 512 threads x 16B x 4 rounds = one 256x64 bf16 panel
  const int rr = tid >> 3;               // row within each 64-row group
  const int gc = (tid & 7) ^ (rr & 7);   // pre-swizzled global chunk (involution)
  const unsigned short* ga = A  + (size_t)(m0 + rr)*K + gc*8;
  const unsigned short* gb = Bt + (size_t)(n0 + rr)*K + gc*8;
  short* la = &Al[0][0] + (size_t)w*512;   // wave-uniform linear LDS dest
  short* lb = &Bl[0][0] + (size_t)w*512;
  // fragment read bases: row-major [256][64], chunk pos = (kh*4+quad) ^ swz
  const short* arow = &Al[0][0] + (wm*128 + lrow)*64;
  const short* brow = &Bl[0][0] + (wn*64  + lrow)*64;
  const int kc = (quad ^ swz) * 8;       // k-half 0; k-half 1 = kc ^ 32
  const int NT = K >> 6;
  f32x4 acc[8][4] = {};

#define STAGE_T(buf, kt)                                                        \
  {                                                                             \
    _Pragma("unroll")                                                           \
    for (int j = 0; j < 4; j++) {                                               \
      cp16(ga + (size_t)(j*64)*K + (size_t)(kt)*64, la + (buf)*16384 + j*4096); \
      cp16(gb + (size_t)(j*64)*K + (size_t)(kt)*64, lb + (buf)*16384 + j*4096); \
    }                                                                           \
  }

  // prologue: tiles 0,1 staged; wait tile 0 landed (tile 1's 8 stay in flight)
  STAGE_T(0, 0);
  STAGE_T(1, 1);
  asm volatile("s_waitcnt vmcnt(8)" ::: "memory");
  __builtin_amdgcn_s_barrier();
  __builtin_amdgcn_sched_barrier(0);

  for (int t = 0; t < NT; ++t) {
    const int cb = (t & 1) * 16384;
    // ---- phase A: k-half 0 ----
    b16x8 af[8], bfr[4];
#pragma unroll
    for (int mi = 0; mi < 8; mi++)
      af[mi] = *(const b16x8*)(arow + cb + mi*1024 + kc);
#pragma unroll
    for (int ni = 0; ni < 4; ni++)
      bfr[ni] = *(const b16x8*)(brow + cb + ni*1024 + kc);
    __builtin_amdgcn_s_setprio(1);
#pragma unroll
    for (int mi = 0; mi < 8; mi++)
#pragma unroll
      for (int ni = 0; ni < 4; ni++)
        acc[mi][ni] = __builtin_amdgcn_mfma_f32_16x16x32_bf16(af[mi], bfr[ni], acc[mi][ni], 0, 0, 0);
    __builtin_amdgcn_s_setprio(0);
    // k-half 1 fragment reads -- the LAST reads of buf[t&1]
    b16x8 af1[8], bf1[4];
#pragma unroll
    for (int mi = 0; mi < 8; mi++)
      af1[mi] = *(const b16x8*)(arow + cb + mi*1024 + (kc ^ 32));
#pragma unroll
    for (int ni = 0; ni < 4; ni++)
      bf1[ni] = *(const b16x8*)(brow + cb + ni*1024 + (kc ^ 32));
    asm volatile("s_waitcnt lgkmcnt(0)" ::: "memory");   // reads done before others stage
    __builtin_amdgcn_s_barrier();                        // all waves finished buf[t&1]
    __builtin_amdgcn_sched_barrier(0);
    // ---- phase B: prefetch tile t+2 into freed buffer, then k-half 1 MFMA ----
    if (t + 2 < NT) STAGE_T(t & 1, t + 2);
    __builtin_amdgcn_sched_barrier(0);
    __builtin_amdgcn_s_setprio(1);
#pragma unroll
    for (int mi = 0; mi < 8; mi++)
#pragma unroll
      for (int ni = 0; ni < 4; ni++)
        acc[mi][ni] = __builtin_amdgcn_mfma_f32_16x16x32_bf16(af1[mi], bf1[ni], acc[mi][ni], 0, 0, 0);
    __builtin_amdgcn_s_setprio(0);
    // tile t+1 must be landed before next iteration's ds_reads; keep t+2 in flight
    if (t + 2 < NT) { asm volatile("s_waitcnt vmcnt(8)" ::: "memory"); }
    else            { asm volatile("s_waitcnt vmcnt(0)" ::: "memory"); }
    __builtin_amdgcn_s_barrier();
    __builtin_amdgcn_sched_barrier(0);
  }
#undef STAGE_T

#pragma unroll
  for (int mi = 0; mi < 8; mi++)
#pragma unroll
    for (int ni = 0; ni < 4; ni++) {
      int col = n0 + wn*64 + ni*16 + lrow;
      float bv = bias ? bias[col] : 0.0f;
#pragma unroll
      for (int r = 0; r < 4; r++) {   // C/D layout: col=lane&15, row=quad*4+r (m89/m91)
        int row = m0 + wm*128 + mi*16 + quad*4 + r;
        C[(size_t)row*N + col] = acc[mi][ni][r] + bv;
      }
    }
}

// ---------------- RoPE (fp32 in, strided) -> bf16 [b*nh+h][s][d], optional scale ----------------
__global__ __launch_bounds__(256) void rope(const float* __restrict__ X, int xstride, int colbase,
                                            const float* __restrict__ cp,
                                            const float* __restrict__ sp,
                                            unsigned short* __restrict__ o, int nh, float scale) {
  int tid = blockIdx.x*256 + threadIdx.x;
  int d = tid & 63;
  int h = (tid >> 6) % nh;
  int m = tid / (64*nh);
  int b = m >> 11, s = m & 2047;
  size_t xoff = (size_t)m*xstride + colbase + (size_t)h*HD + d;
  float x1 = X[xoff], x2 = X[xoff + 64];
  const float* cb = cp + ((size_t)b*Ss + s)*HD;
  const float* sb = sp + ((size_t)b*Ss + s)*HD;
  float o1 = (x1*cb[d]      - x2*sb[d])      * scale;
  float o2 = (x2*cb[d + 64] + x1*sb[d + 64]) * scale;
  unsigned short* ob = o + ((size_t)(b*nh + h)*Ss + s)*HD;
  ob[d]      = f2bf(o1);
  ob[d + 64] = f2bf(o2);
}

// ---------------- V fp32 (strided cols) -> f16 Vt [b*NKV+kvh][d][s] ----------------
__global__ __launch_bounds__(256) void vprep(const float* __restrict__ Vf, int xstride, int colbase,
                                             _Float16* __restrict__ Vt) {
  __shared__ float t[32][33];
  int dt = blockIdx.x, st = blockIdx.y, bk = blockIdx.z;
  int b = bk >> 3, kvh = bk & 7;
  int tx = threadIdx.x & 31, ty = threadIdx.x >> 5;
#pragma unroll
  for (int i = 0; i < 4; i++) {
    int s = st*32 + ty + i*8;
    t[ty + i*8][tx] = Vf[(size_t)(b*Ss + s)*xstride + colbase + kvh*HD + dt*32 + tx];
  }
  __syncthreads();
#pragma unroll
  for (int i = 0; i < 4; i++) {
    int d = dt*32 + ty + i*8;
    Vt[((size_t)bk*HD + d)*Ss + st*32 + tx] = (_Float16)t[tx][ty + i*8];
  }
}

// ---------------- flash attention: BLOCK_Q=64 (4 waves x 16 rows), BLOCK_K=64 ----------------
// Fixed-max softmax in exp2 domain (Q pre-scaled by log2e/sqrt(HD)); P,V in f16;
// row-sum l accumulated via MFMA ones-column (V-tile row d=128 == 1.0).
// K LDS: chunk c of key-row r at r*16 + (c ^ (r&7));  V LDS: chunk c of d-row at d*8 + (c ^ (d&7))
__global__ __launch_bounds__(256) void flash(const unsigned short* __restrict__ Qr,
                                             const unsigned short* __restrict__ Kr,
                                             const _Float16* __restrict__ Vt,
                                             unsigned short* __restrict__ AO) {
  __shared__ short Kl[64*128];       // 16KB, swizzled, bf16
  __shared__ short Vl[144*64];       // 18KB, swizzled, f16; rows 128..143: ones-row + zeros
  __shared__ _Float16 Pl[4][16*72];  // 9KB, padded (stride 72 = 4 mod 32 banks, 16B-aligned rows)
  const int qt = blockIdx.x, h = blockIdx.y, b = blockIdx.z;
  const int tid = threadIdx.x, w = tid >> 6, lane = tid & 63;
  const int lrow = lane & 15, quad = lane >> 4;
  const int wb = tid & 192;
  const int swz = lrow & 7;                 // read-side chunk swizzle
  const int kvh = h >> 2;                   // GROUPS=4
  const unsigned short* Qb = Qr + ((size_t)(b*NH + h)*Ss + qt*64 + w*16)*HD;
  const unsigned short* Kb = Kr + ((size_t)(b*NKV + kvh)*Ss)*HD;
  const _Float16*       Vb = Vt + ((size_t)(b*NKV + kvh)*HD)*Ss;
  // ones region init (rows 128..143): row 128 = 1.0h, rest 0
  {
    int idx = tid*4;
    int row = 128 + (idx >> 6);
    unsigned short v = (row == 128) ? 0x3C00u : 0u;
    ushort4 vv; vv.x = v; vv.y = v; vv.z = v; vv.w = v;
    *(ushort4*)((unsigned short*)Vl + 128*64 + idx) = vv;
  }
  b16x8 qf[4];                              // A-frag: A[m=lane&15][k=quad*8+j]; Q pre-scaled
#pragma unroll
  for (int t = 0; t < 4; t++)
    qf[t] = *(const b16x8*)(Qb + (size_t)lrow*HD + t*32 + quad*8);
  f32x4 o[8] = {};
  f32x4 ol = {};                            // ones-column accumulator (row sums l)
  for (int kt = 0; kt < 32; kt++) {
    __syncthreads();
#pragma unroll
    for (int i = 0; i < 4; i++) {           // K tile: 64 keys x 128 d (bf16), swizzled
      int c = i*256 + tid;
      int r = c >> 4, gc = (c & 15) ^ (r & 7);
      cp16(Kb + (size_t)(kt*64 + r)*HD + gc*8, Kl + (i*256 + wb)*8);
    }
#pragma unroll
    for (int i = 0; i < 4; i++) {           // V tile: 128 d x 64 keys (f16), swizzled
      int c = i*256 + tid;
      int r = c >> 3, gc = (c & 7) ^ (r & 7);
      cp16(Vb + (size_t)r*Ss + kt*64 + gc*8, Vl + (i*256 + wb)*8);
    }
    __syncthreads();
    f32x4 sc[4] = {};
#pragma unroll
    for (int t = 0; t < 4; t++)
#pragma unroll
      for (int n = 0; n < 4; n++) {
        b16x8 kf = *(const b16x8*)(Kl + (n*16 + lrow)*128 + ((t*4 + quad) ^ swz)*8);
        sc[n] = __builtin_amdgcn_mfma_f32_16x16x32_bf16(qf[t], kf, sc[n], 0, 0, 0);
      }
    // p = exp2(sc)  (scores pre-scaled to log2 domain; no max subtraction — cancels in o/l)
#pragma unroll
    for (int n = 0; n < 4; n++)
#pragma unroll
      for (int r = 0; r < 4; r++)
        Pl[w][(quad*4 + r)*72 + n*16 + lrow] = (_Float16)__builtin_amdgcn_exp2f(sc[n][r]);
    // no barrier: Pl[w] is per-wave (same-wave DS ops in-order); Vl guarded by loop-top barrier
#pragma unroll
    for (int st = 0; st < 2; st++) {
      f16x8 pf = *(const f16x8*)(&Pl[w][lrow*72 + st*32 + quad*8]);
#pragma unroll
      for (int n = 0; n < 8; n++) {
        f16x8 vf = *(const f16x8*)((const _Float16*)Vl + (n*16 + lrow)*64 + ((st*4 + quad) ^ swz)*8);
        o[n] = __builtin_amdgcn_mfma_f32_16x16x32_f16(pf, vf, o[n], 0, 0, 0);
      }
      f16x8 vf1 = *(const f16x8*)((const _Float16*)Vl + (128 + lrow)*64 + ((st*4 + quad) ^ swz)*8);
      ol = __builtin_amdgcn_mfma_f32_16x16x32_f16(pf, vf1, ol, 0, 0, 0);
    }
  }
  // l lives in column 0 of the ones-tile -> lane quad*16, reg r = row quad*4+r
  float rl[4];
#pragma unroll
  for (int r = 0; r < 4; r++)
    rl[r] = 1.0f / __shfl(ol[r], lane & 48);
  const int s0 = qt*64 + w*16;
#pragma unroll
  for (int n = 0; n < 8; n++)
#pragma unroll
    for (int r = 0; r < 4; r++) {
      int srow = s0 + quad*4 + r;
      float v = o[n][r] * rl[r];
      AO[((size_t)(b*Ss + srow))*HID + h*HD + n*16 + lrow] = f2bf(v);
    }
}

extern "C" void kernel_launch(void* const* d_in, const int* in_sizes, int n_in,
                              void* d_out, int out_size, void* d_ws, size_t ws_size,
                              hipStream_t stream) {
  (void)in_sizes; (void)n_in; (void)out_size; (void)ws_size;
  const float* hs   = (const float*)d_in[0];
  const float* cosp = (const float*)d_in[1];
  const float* sinp = (const float*)d_in[2];
  const float* Wq   = (const float*)d_in[3];
  const float* bq   = (const float*)d_in[4];
  const float* Wk   = (const float*)d_in[5];
  const float* bk   = (const float*)d_in[6];
  const float* Wv   = (const float*)d_in[7];
  const float* bv   = (const float*)d_in[8];
  const float* Wo   = (const float*)d_in[9];
  float* out = (float*)d_out;
  const float QSC = 0.12751742826919558f;   // log2(e)/sqrt(128): exp2-domain softmax

  // workspace layout (~218 MiB, liveness-aliased)
  char* p = (char*)d_ws;
  unsigned short* Xb   = (unsigned short*)p; p += (size_t)Mrows*HID*2;     // 33.5MB
  unsigned short* Wcat = (unsigned short*)p; p += (size_t)NQKV*HID*2;      // 50.3MB  [Wq|Wk|Wv] rows
  unsigned short* Wot  = (unsigned short*)p; p += (size_t)HID*HID*2;       // 33.5MB
  float* bcat = (float*)p; p += (size_t)NQKV*4;                            // 24KB
  float* QKVf = (float*)p; p += (size_t)Mrows*NQKV*4;                      // 100.7MB
  // aliases (dead-after under stream ordering):
  unsigned short* Qr = Xb;                                    // Xb dead after QKV GEMM
  unsigned short* Kr = Wcat;                                  // Wcat dead after QKV GEMM
  _Float16*       Vt = (_Float16*)(Wcat + (size_t)(Bz*NKV)*Ss*HD);  // 8.4+8.4 <= 50.3MB
  unsigned short* AO = (unsigned short*)QKVf;                 // QKVf dead after rope/vprep

  // 1) prologue casts/transposes
  cast_x<<<Mrows*HID/1024, 256, 0, stream>>>(hs, Xb);
  wtrans<<<dim3(HID/32, HID/32),      256, 0, stream>>>(Wq, Wcat,                        HID, HID);
  wtrans<<<dim3((NKV*HD)/32, HID/32), 256, 0, stream>>>(Wk, Wcat + (size_t)4096*HID,     HID, NKV*HD);
  wtrans<<<dim3((NKV*HD)/32, HID/32), 256, 0, stream>>>(Wv, Wcat + (size_t)5120*HID,     HID, NKV*HD);
  wtrans<<<dim3(HID/32, HID/32),      256, 0, stream>>>(Wo, Wot, HID, HID);
  bias_cat<<<NQKV/256, 256, 0, stream>>>(bq, bk, bv, bcat);

  // 2) fused QKV projection (fp32 out for RoPE precision) — 256² counted-vmcnt GEMM
  gemm_bt<<<dim3(NQKV/256, Mrows/256), 512, 0, stream>>>(Xb, Wcat, bcat, QKVf, NQKV, HID);

  // 3) RoPE + layout transforms (Q pre-scaled into exp2 domain)
  rope<<<(Mrows*NH*64)/256,  256, 0, stream>>>(QKVf, NQKV, 0,    cosp, sinp, Qr, NH,  QSC);
  rope<<<(Mrows*NKV*64)/256, 256, 0, stream>>>(QKVf, NQKV, 4096, cosp, sinp, Kr, NKV, 1.0f);
  vprep<<<dim3(HD/32, Ss/32, Bz*NKV), 256, 0, stream>>>(QKVf, NQKV, 5120, Vt);

  // 4) flash attention -> AO bf16 [b*s][h*HD+d]
  flash<<<dim3(Ss/64, NH, Bz), 256, 0, stream>>>(Qr, Kr, Vt, AO);

  // 5) output projection -> d_out fp32
  gemm_bt<<<dim3(HID/256, Mrows/256), 512, 0, stream>>>(AO, Wot, nullptr, out, HID, HID);
}

// Round 3
// 840.764 us; speedup vs baseline: 1.1597x; 1.0277x over previous
//
#include <hip/hip_runtime.h>
#include <stdint.h>

#define Bz   2
#define Ss   2048
#define HID  4096
#define NH   32
#define NKV  8
#define HD   128
#define Mrows (Bz*Ss)   // 4096
#define NQKV 6144       // 4096 Q + 1024 K + 1024 V

typedef __attribute__((ext_vector_type(8))) short b16x8;       // 8 bf16 (4 VGPRs)
typedef __attribute__((ext_vector_type(8))) _Float16 f16x8;    // 8 f16  (4 VGPRs)
typedef __attribute__((ext_vector_type(4))) float f32x4;

__device__ __forceinline__ unsigned short f2bf(float f) {
  union { float f; uint32_t u; } v; v.f = f;
  uint32_t r = v.u + 0x7FFFu + ((v.u >> 16) & 1u);   // RNE
  return (unsigned short)(r >> 16);
}

// async global->LDS, 16B per lane; LDS dest = wave-uniform base + lane*16
__device__ __forceinline__ void cp16(const void* g, void* l) {
  __builtin_amdgcn_global_load_lds(
      (const __attribute__((address_space(1))) void*)g,
      (__attribute__((address_space(3))) void*)l, 16, 0, 0);
}

// ---------------- elementwise cast: fp32 -> bf16 (float4 loads) ----------------
__global__ __launch_bounds__(256) void cast_x(const float* __restrict__ x,
                                              unsigned short* __restrict__ o) {
  int i = blockIdx.x*256 + threadIdx.x;
  float4 v = ((const float4*)x)[i];
  ushort4 r; r.x = f2bf(v.x); r.y = f2bf(v.y); r.z = f2bf(v.z); r.w = f2bf(v.w);
  ((ushort4*)o)[i] = r;
}

// ---------------- W[k][n] fp32 -> Wt[n][k] bf16 (32x32 LDS tile) ----------------
__global__ __launch_bounds__(256) void wtrans(const float* __restrict__ W,
                                              unsigned short* __restrict__ Wt,
                                              int K, int N) {
  __shared__ float t[32][33];
  int n0 = blockIdx.x*32, k0 = blockIdx.y*32;
  int tx = threadIdx.x & 31, ty = threadIdx.x >> 5;
#pragma unroll
  for (int i = 0; i < 4; i++)
    t[ty + i*8][tx] = W[(size_t)(k0 + ty + i*8)*N + n0 + tx];
  __syncthreads();
#pragma unroll
  for (int i = 0; i < 4; i++)
    Wt[(size_t)(n0 + ty + i*8)*K + k0 + tx] = f2bf(t[tx][ty + i*8]);
}

// ---------------- bias concat: [bq | bk | bv] ----------------
__global__ __launch_bounds__(256) void bias_cat(const float* __restrict__ bq,
                                                const float* __restrict__ bk,
                                                const float* __restrict__ bv,
                                                float* __restrict__ o) {
  int i = blockIdx.x*256 + threadIdx.x;
  float v = (i < 4096) ? bq[i] : (i < 5120) ? bk[i-4096] : bv[i-5120];
  o[i] = v;
}

// ---------------- C(MxN,f32) = A(MxK,bf16) @ Bt(NxK,bf16)^T + bias ----------------
// m201-port: 256x256 tile, BK=64, 8 waves (2M x 4N), 128KB dbuf LDS, 8-phase
// fine interleave (4 phases/K-tile), counted vmcnt(6) once per K-tile (never 0
// in steady state), setprio around MFMA clusters, XOR chunk swizzle.
// LDS regions (shorts):  A buf: [h][wm][64][64]  h=row-quarter pair consumed by
// phase 1 (h=0: rows 0-63,128-191) / phase 3 (h=1).  B buf: [h][wn][32][64]
// h=0: first 32 rows of each 64-row wn-block (consumed phase 1) / h=1 (phase 2).
// Half-tile stream order per K-tile: A.h0, B.h0, B.h1, A.h1 (2 loads/thread each).
// Steady state: at tile t's phase-4 vmcnt(6), 3 half-tiles (t+2.{A.h0,B.h0,B.h1})
// stay in flight; t+1 is fully landed. Each stage targets a region whose last
// reader passed lgkmcnt(0)+barrier. Requires K multiple of 64, K>=128 here.
__global__ __launch_bounds__(512, 2) void gemm_bt(const unsigned short* __restrict__ A,
                                                  const unsigned short* __restrict__ Bt,
                                                  const float* __restrict__ bias,
                                                  float* __restrict__ C,
                                                  int N, int K) {
  __shared__ __align__(16) short Al[2*16384];   // 64KB: [buf][h][wm][64][64]
  __shared__ __align__(16) short Bl[2*16384];   // 64KB: [buf][h][wn][32][64]
  const int tid = threadIdx.x;
  const int w = tid >> 6, lane = tid & 63;
  const int wm = w >> 2, wn = w & 3;
  const int lrow = lane & 15, quad = lane >> 4;
  const int swz = lrow & 7;
  // T1: bijective XCD swizzle (both launches have nwg % 8 == 0)
  int bid = blockIdx.y * gridDim.x + blockIdx.x;
  const int nwg = gridDim.x * gridDim.y;
  bid = (bid & 7) * (nwg >> 3) + (bid >> 3);
  const int m0 = (bid / gridDim.x) * 256;
  const int n0 = (bid % gridDim.x) * 256;
  // staging geometry: per half-tile, 512 threads x 2 loads x 16B = 16KB
  const int srA = (tid >> 3) & 63;               // row within A region
  const int srB = (tid >> 3) & 31;               // row within B region
  const int gcA = (tid & 7) ^ (srA & 7);         // pre-swizzled source chunk
  const int gcB = (tid & 7) ^ (srB & 7);
  const unsigned short* gaA = A  + (size_t)(m0 + srA)*K + gcA*8;
  const unsigned short* gaB = Bt + (size_t)(n0 + (tid >> 8)*64 + srB)*K + gcB*8;
  const int wbs = w*512;                         // wave-uniform LDS stage base (shorts)

#define SB0() __builtin_amdgcn_sched_barrier(0)
#define STAGE_A(buf, t, h) do {                                                         \
    cp16(gaA + (size_t)((h)*64      )*K + (size_t)(t)*64, Al + (buf)*16384 + (h)*8192        + wbs); \
    cp16(gaA + (size_t)((h)*64 + 128)*K + (size_t)(t)*64, Al + (buf)*16384 + (h)*8192 + 4096 + wbs); \
  } while (0)
#define STAGE_B(buf, t, h) do {                                                         \
    cp16(gaB + (size_t)((h)*32      )*K + (size_t)(t)*64, Bl + (buf)*16384 + (h)*8192        + wbs); \
    cp16(gaB + (size_t)((h)*32 + 128)*K + (size_t)(t)*64, Bl + (buf)*16384 + (h)*8192 + 4096 + wbs); \
  } while (0)

  // fragment read bases (shorts): a(mi,kh) = (mi>>2)*8192 + wm*4096 + ((mi&3)*16+lrow)*64 + kc
  const short* Ar = Al + wm*4096 + lrow*64;
  const short* Br = Bl + wn*2048 + lrow*64;
  const int kc0 = (quad ^ swz) * 8;              // kh=0 chunk; kh=1 = kc0^32
  const int NT = K >> 6;
  f32x4 acc[8][4] = {};

  // ---- prologue: tile0 (4 halves) + tile1 (first 3 halves); vmcnt(6) = tile0 landed
  STAGE_A(0, 0, 0); SB0(); STAGE_B(0, 0, 0); SB0();
  STAGE_B(0, 0, 1); SB0(); STAGE_A(0, 0, 1); SB0();
  if (NT > 1) { STAGE_A(1, 1, 0); SB0(); STAGE_B(1, 1, 0); SB0(); STAGE_B(1, 1, 1); SB0(); }
  if (NT > 1) { asm volatile("s_waitcnt vmcnt(6)" ::: "memory"); }
  else        { asm volatile("s_waitcnt vmcnt(0)" ::: "memory"); }
  __builtin_amdgcn_s_barrier();
  SB0();

  for (int t = 0; t < NT; ++t) {
    const int cb = (t & 1) * 16384;
    b16x8 a0[4][2], a1[4][2], b0[2][2], b1[2][2];
    // ---- phase 1: read A-lo(8) + B-lo(4); stage (t+1).A.h1; MFMA mi0-3 x ni0-1
#pragma unroll
    for (int mi = 0; mi < 4; mi++) {
      a0[mi][0] = *(const b16x8*)(Ar + cb + mi*1024 + kc0);
      a0[mi][1] = *(const b16x8*)(Ar + cb + mi*1024 + (kc0 ^ 32));
    }
#pragma unroll
    for (int ni = 0; ni < 2; ni++) {
      b0[ni][0] = *(const b16x8*)(Br + cb + ni*1024 + kc0);
      b0[ni][1] = *(const b16x8*)(Br + cb + ni*1024 + (kc0 ^ 32));
    }
    if (t + 1 < NT) STAGE_A((t + 1) & 1, t + 1, 1);
    __builtin_amdgcn_s_barrier();
    asm volatile("s_waitcnt lgkmcnt(0)" ::: "memory");
    SB0();
    __builtin_amdgcn_s_setprio(1);
#pragma unroll
    for (int mi = 0; mi < 4; mi++)
#pragma unroll
      for (int ni = 0; ni < 2; ni++) {
        acc[mi][ni] = __builtin_amdgcn_mfma_f32_16x16x32_bf16(a0[mi][0], b0[ni][0], acc[mi][ni], 0, 0, 0);
        acc[mi][ni] = __builtin_amdgcn_mfma_f32_16x16x32_bf16(a0[mi][1], b0[ni][1], acc[mi][ni], 0, 0, 0);
      }
    __builtin_amdgcn_s_setprio(0);
    __builtin_amdgcn_s_barrier();
    // ---- phase 2: read B-hi(4); stage (t+2).A.h0; MFMA mi0-3 x ni2-3
#pragma unroll
    for (int ni = 0; ni < 2; ni++) {
      b1[ni][0] = *(const b16x8*)(Br + cb + 8192 + ni*1024 + kc0);
      b1[ni][1] = *(const b16x8*)(Br + cb + 8192 + ni*1024 + (kc0 ^ 32));
    }
    if (t + 2 < NT) STAGE_A(t & 1, t + 2, 0);
    __builtin_amdgcn_s_barrier();
    asm volatile("s_waitcnt lgkmcnt(0)" ::: "memory");
    SB0();
    __builtin_amdgcn_s_setprio(1);
#pragma unroll
    for (int mi = 0; mi < 4; mi++)
#pragma unroll
      for (int ni = 0; ni < 2; ni++) {
        acc[mi][ni+2] = __builtin_amdgcn_mfma_f32_16x16x32_bf16(a0[mi][0], b1[ni][0], acc[mi][ni+2], 0, 0, 0);
        acc[mi][ni+2] = __builtin_amdgcn_mfma_f32_16x16x32_bf16(a0[mi][1], b1[ni][1], acc[mi][ni+2], 0, 0, 0);
      }
    __builtin_amdgcn_s_setprio(0);
    __builtin_amdgcn_s_barrier();
    // ---- phase 3: read A-hi(8); stage (t+2).B.h0; MFMA mi4-7 x ni0-1
#pragma unroll
    for (int mi = 0; mi < 4; mi++) {
      a1[mi][0] = *(const b16x8*)(Ar + cb + 8192 + mi*1024 + kc0);
      a1[mi][1] = *(const b16x8*)(Ar + cb + 8192 + mi*1024 + (kc0 ^ 32));
    }
    if (t + 2 < NT) STAGE_B(t & 1, t + 2, 0);
    __builtin_amdgcn_s_barrier();
    asm volatile("s_waitcnt lgkmcnt(0)" ::: "memory");
    SB0();
    __builtin_amdgcn_s_setprio(1);
#pragma unroll
    for (int mi = 0; mi < 4; mi++)
#pragma unroll
      for (int ni = 0; ni < 2; ni++) {
        acc[mi+4][ni] = __builtin_amdgcn_mfma_f32_16x16x32_bf16(a1[mi][0], b0[ni][0], acc[mi+4][ni], 0, 0, 0);
        acc[mi+4][ni] = __builtin_amdgcn_mfma_f32_16x16x32_bf16(a1[mi][1], b0[ni][1], acc[mi+4][ni], 0, 0, 0);
      }
    __builtin_amdgcn_s_setprio(0);
    __builtin_amdgcn_s_barrier();
    // ---- phase 4: stage (t+2).B.h1; counted vmcnt; MFMA mi4-7 x ni2-3
    if (t + 2 < NT) {
      STAGE_B(t & 1, t + 2, 1);
      asm volatile("s_waitcnt vmcnt(6)" ::: "memory");   // t+1 landed; t+2 halves in flight
    } else {
      asm volatile("s_waitcnt vmcnt(0)" ::: "memory");   // tail drain
    }
    __builtin_amdgcn_s_barrier();
    SB0();
    __builtin_amdgcn_s_setprio(1);
#pragma unroll
    for (int mi = 0; mi < 4; mi++)
#pragma unroll
      for (int ni = 0; ni < 2; ni++) {
        acc[mi+4][ni+2] = __builtin_amdgcn_mfma_f32_16x16x32_bf16(a1[mi][0], b1[ni][0], acc[mi+4][ni+2], 0, 0, 0);
        acc[mi+4][ni+2] = __builtin_amdgcn_mfma_f32_16x16x32_bf16(a1[mi][1], b1[ni][1], acc[mi+4][ni+2], 0, 0, 0);
      }
    __builtin_amdgcn_s_setprio(0);
    __builtin_amdgcn_s_barrier();
    SB0();
  }
#undef STAGE_A
#undef STAGE_B
#undef SB0

#pragma unroll
  for (int mi = 0; mi < 8; mi++)
#pragma unroll
    for (int ni = 0; ni < 4; ni++) {
      int col = n0 + wn*64 + ni*16 + lrow;
      float bv = bias ? bias[col] : 0.0f;
#pragma unroll
      for (int r = 0; r < 4; r++) {   // C/D layout: col=lane&15, row=quad*4+r (m89/m91)
        int row = m0 + wm*128 + mi*16 + quad*4 + r;
        C[(size_t)row*N + col] = acc[mi][ni][r] + bv;
      }
    }
}

// ---------------- RoPE (fp32 in, strided) -> bf16 [b*nh+h][s][d], optional scale ----------------
__global__ __launch_bounds__(256) void rope(const float* __restrict__ X, int xstride, int colbase,
                                            const float* __restrict__ cp,
                                            const float* __restrict__ sp,
                                            unsigned short* __restrict__ o, int nh, float scale) {
  int tid = blockIdx.x*256 + threadIdx.x;
  int d = tid & 63;
  int h = (tid >> 6) % nh;
  int m = tid / (64*nh);
  int b = m >> 11, s = m & 2047;
  size_t xoff = (size_t)m*xstride + colbase + (size_t)h*HD + d;
  float x1 = X[xoff], x2 = X[xoff + 64];
  const float* cb = cp + ((size_t)b*Ss + s)*HD;
  const float* sb = sp + ((size_t)b*Ss + s)*HD;
  float o1 = (x1*cb[d]      - x2*sb[d])      * scale;
  float o2 = (x2*cb[d + 64] + x1*sb[d + 64]) * scale;
  unsigned short* ob = o + ((size_t)(b*nh + h)*Ss + s)*HD;
  ob[d]      = f2bf(o1);
  ob[d + 64] = f2bf(o2);
}

// ---------------- V fp32 (strided cols) -> f16 Vt [b*NKV+kvh][d][s] ----------------
__global__ __launch_bounds__(256) void vprep(const float* __restrict__ Vf, int xstride, int colbase,
                                             _Float16* __restrict__ Vt) {
  __shared__ float t[32][33];
  int dt = blockIdx.x, st = blockIdx.y, bk = blockIdx.z;
  int b = bk >> 3, kvh = bk & 7;
  int tx = threadIdx.x & 31, ty = threadIdx.x >> 5;
#pragma unroll
  for (int i = 0; i < 4; i++) {
    int s = st*32 + ty + i*8;
    t[ty + i*8][tx] = Vf[(size_t)(b*Ss + s)*xstride + colbase + kvh*HD + dt*32 + tx];
  }
  __syncthreads();
#pragma unroll
  for (int i = 0; i < 4; i++) {
    int d = dt*32 + ty + i*8;
    Vt[((size_t)bk*HD + d)*Ss + st*32 + tx] = (_Float16)t[tx][ty + i*8];
  }
}

// ---------------- flash attention: BLOCK_Q=64 (4 waves x 16 rows), BLOCK_K=64 ----------------
// Fixed-max softmax in exp2 domain (Q pre-scaled by log2e/sqrt(HD)); P,V in f16;
// row-sum l accumulated via MFMA ones-column (V-tile row d=128 == 1.0).
// K LDS: chunk c of key-row r at r*16 + (c ^ (r&7));  V LDS: chunk c of d-row at d*8 + (c ^ (d&7))
__global__ __launch_bounds__(256) void flash(const unsigned short* __restrict__ Qr,
                                             const unsigned short* __restrict__ Kr,
                                             const _Float16* __restrict__ Vt,
                                             unsigned short* __restrict__ AO) {
  __shared__ short Kl[64*128];       // 16KB, swizzled, bf16
  __shared__ short Vl[144*64];       // 18KB, swizzled, f16; rows 128..143: ones-row + zeros
  __shared__ _Float16 Pl[4][16*72];  // 9KB, padded (stride 72 = 4 mod 32 banks, 16B-aligned rows)
  const int qt = blockIdx.x, h = blockIdx.y, b = blockIdx.z;
  const int tid = threadIdx.x, w = tid >> 6, lane = tid & 63;
  const int lrow = lane & 15, quad = lane >> 4;
  const int wb = tid & 192;
  const int swz = lrow & 7;                 // read-side chunk swizzle
  const int kvh = h >> 2;                   // GROUPS=4
  const unsigned short* Qb = Qr + ((size_t)(b*NH + h)*Ss + qt*64 + w*16)*HD;
  const unsigned short* Kb = Kr + ((size_t)(b*NKV + kvh)*Ss)*HD;
  const _Float16*       Vb = Vt + ((size_t)(b*NKV + kvh)*HD)*Ss;
  // ones region init (rows 128..143): row 128 = 1.0h, rest 0
  {
    int idx = tid*4;
    int row = 128 + (idx >> 6);
    unsigned short v = (row == 128) ? 0x3C00u : 0u;
    ushort4 vv; vv.x = v; vv.y = v; vv.z = v; vv.w = v;
    *(ushort4*)((unsigned short*)Vl + 128*64 + idx) = vv;
  }
  b16x8 qf[4];                              // A-frag: A[m=lane&15][k=quad*8+j]; Q pre-scaled
#pragma unroll
  for (int t = 0; t < 4; t++)
    qf[t] = *(const b16x8*)(Qb + (size_t)lrow*HD + t*32 + quad*8);
  f32x4 o[8] = {};
  f32x4 ol = {};                            // ones-column accumulator (row sums l)
  for (int kt = 0; kt < 32; kt++) {
    __syncthreads();
#pragma unroll
    for (int i = 0; i < 4; i++) {           // K tile: 64 keys x 128 d (bf16), swizzled
      int c = i*256 + tid;
      int r = c >> 4, gc = (c & 15) ^ (r & 7);
      cp16(Kb + (size_t)(kt*64 + r)*HD + gc*8, Kl + (i*256 + wb)*8);
    }
#pragma unroll
    for (int i = 0; i < 4; i++) {           // V tile: 128 d x 64 keys (f16), swizzled
      int c = i*256 + tid;
      int r = c >> 3, gc = (c & 7) ^ (r & 7);
      cp16(Vb + (size_t)r*Ss + kt*64 + gc*8, Vl + (i*256 + wb)*8);
    }
    __syncthreads();
    f32x4 sc[4] = {};
#pragma unroll
    for (int t = 0; t < 4; t++)
#pragma unroll
      for (int n = 0; n < 4; n++) {
        b16x8 kf = *(const b16x8*)(Kl + (n*16 + lrow)*128 + ((t*4 + quad) ^ swz)*8);
        sc[n] = __builtin_amdgcn_mfma_f32_16x16x32_bf16(qf[t], kf, sc[n], 0, 0, 0);
      }
    // p = exp2(sc)  (scores pre-scaled to log2 domain; no max subtraction — cancels in o/l)
#pragma unroll
    for (int n = 0; n < 4; n++)
#pragma unroll
      for (int r = 0; r < 4; r++)
        Pl[w][(quad*4 + r)*72 + n*16 + lrow] = (_Float16)__builtin_amdgcn_exp2f(sc[n][r]);
    // no barrier: Pl[w] is per-wave (same-wave DS ops in-order); Vl guarded by loop-top barrier
#pragma unroll
    for (int st = 0; st < 2; st++) {
      f16x8 pf = *(const f16x8*)(&Pl[w][lrow*72 + st*32 + quad*8]);
#pragma unroll
      for (int n = 0; n < 8; n++) {
        f16x8 vf = *(const f16x8*)((const _Float16*)Vl + (n*16 + lrow)*64 + ((st*4 + quad) ^ swz)*8);
        o[n] = __builtin_amdgcn_mfma_f32_16x16x32_f16(pf, vf, o[n], 0, 0, 0);
      }
      f16x8 vf1 = *(const f16x8*)((const _Float16*)Vl + (128 + lrow)*64 + ((st*4 + quad) ^ swz)*8);
      ol = __builtin_amdgcn_mfma_f32_16x16x32_f16(pf, vf1, ol, 0, 0, 0);
    }
  }
  // l lives in column 0 of the ones-tile -> lane quad*16, reg r = row quad*4+r
  float rl[4];
#pragma unroll
  for (int r = 0; r < 4; r++)
    rl[r] = 1.0f / __shfl(ol[r], lane & 48);
  const int s0 = qt*64 + w*16;
#pragma unroll
  for (int n = 0; n < 8; n++)
#pragma unroll
    for (int r = 0; r < 4; r++) {
      int srow = s0 + quad*4 + r;
      float v = o[n][r] * rl[r];
      AO[((size_t)(b*Ss + srow))*HID + h*HD + n*16 + lrow] = f2bf(v);
    }
}

extern "C" void kernel_launch(void* const* d_in, const int* in_sizes, int n_in,
                              void* d_out, int out_size, void* d_ws, size_t ws_size,
                              hipStream_t stream) {
  (void)in_sizes; (void)n_in; (void)out_size; (void)ws_size;
  const float* hs   = (const float*)d_in[0];
  const float* cosp = (const float*)d_in[1];
  const float* sinp = (const float*)d_in[2];
  const float* Wq   = (const float*)d_in[3];
  const float* bq   = (const float*)d_in[4];
  const float* Wk   = (const float*)d_in[5];
  const float* bk   = (const float*)d_in[6];
  const float* Wv   = (const float*)d_in[7];
  const float* bv   = (const float*)d_in[8];
  const float* Wo   = (const float*)d_in[9];
  float* out = (float*)d_out;
  const float QSC = 0.12751742826919558f;   // log2(e)/sqrt(128): exp2-domain softmax

  // workspace layout (~218 MiB, liveness-aliased)
  char* p = (char*)d_ws;
  unsigned short* Xb   = (unsigned short*)p; p += (size_t)Mrows*HID*2;     // 33.5MB
  unsigned short* Wcat = (unsigned short*)p; p += (size_t)NQKV*HID*2;      // 50.3MB  [Wq|Wk|Wv] rows
  unsigned short* Wot  = (unsigned short*)p; p += (size_t)HID*HID*2;       // 33.5MB
  float* bcat = (float*)p; p += (size_t)NQKV*4;                            // 24KB
  float* QKVf = (float*)p; p += (size_t)Mrows*NQKV*4;                      // 100.7MB
  // aliases (dead-after under stream ordering):
  unsigned short* Qr = Xb;                                    // Xb dead after QKV GEMM
  unsigned short* Kr = Wcat;                                  // Wcat dead after QKV GEMM
  _Float16*       Vt = (_Float16*)(Wcat + (size_t)(Bz*NKV)*Ss*HD);  // 8.4+8.4 <= 50.3MB
  unsigned short* AO = (unsigned short*)QKVf;                 // QKVf dead after rope/vprep

  // 1) prologue casts/transposes
  cast_x<<<Mrows*HID/1024, 256, 0, stream>>>(hs, Xb);
  wtrans<<<dim3(HID/32, HID/32),      256, 0, stream>>>(Wq, Wcat,                        HID, HID);
  wtrans<<<dim3((NKV*HD)/32, HID/32), 256, 0, stream>>>(Wk, Wcat + (size_t)4096*HID,     HID, NKV*HD);
  wtrans<<<dim3((NKV*HD)/32, HID/32), 256, 0, stream>>>(Wv, Wcat + (size_t)5120*HID,     HID, NKV*HD);
  wtrans<<<dim3(HID/32, HID/32),      256, 0, stream>>>(Wo, Wot, HID, HID);
  bias_cat<<<NQKV/256, 256, 0, stream>>>(bq, bk, bv, bcat);

  // 2) fused QKV projection (fp32 out for RoPE precision) — 256² 8-phase GEMM
  gemm_bt<<<dim3(NQKV/256, Mrows/256), 512, 0, stream>>>(Xb, Wcat, bcat, QKVf, NQKV, HID);

  // 3) RoPE + layout transforms (Q pre-scaled into exp2 domain)
  rope<<<(Mrows*NH*64)/256,  256, 0, stream>>>(QKVf, NQKV, 0,    cosp, sinp, Qr, NH,  QSC);
  rope<<<(Mrows*NKV*64)/256, 256, 0, stream>>>(QKVf, NQKV, 4096, cosp, sinp, Kr, NKV, 1.0f);
  vprep<<<dim3(HD/32, Ss/32, Bz*NKV), 256, 0, stream>>>(QKVf, NQKV, 5120, Vt);

  // 4) flash attention -> AO bf16 [b*s][h*HD+d]
  flash<<<dim3(Ss/64, NH, Bz), 256, 0, stream>>>(Qr, Kr, Vt, AO);

  // 5) output projection -> d_out fp32
  gemm_bt<<<dim3(HID/256, Mrows/256), 512, 0, stream>>>(AO, Wot, nullptr, out, HID, HID);
}